// Round 7
// baseline (152.736 us; speedup 1.0000x reference)
//
#include <hip/hip_runtime.h>

// Problem constants (hardcoded in reference)
constexpr int NB = 4096;  // batch
constexpr int NT = 128;   // TEXT_LEN
constexpr int NS = 128;   // retweet_user_size
constexpr int ND = 32;    // feature dim

// Math identity: softmax over a trailing axis of size 1 == 1.0, so
//   out[b, 0:32]  = sum_s X1[b,s,:]
//   out[b, 32:64] = sum_t C[b,t,:]
// Pure streaming column-sum (~134 MB read, 1 MB write).
//
// Round-3: wave-per-batch, Occ 30%, 44-48us.
// Round-6: wave-per-(batch,tensor), Occ 52%, 43us  -> occupancy was NOT the
//   limiter. VGPR_Count=24 showed the compiler kept only ~2 loads in flight
//   (single-accumulator chain let it reuse 2 dest regs + vmcnt between) ->
//   ~8 serialized memory round-trips per wave; latency-bound at 3.1 TB/s.
//
// This round: force MLP. 16 NAMED independent float4 loads issued before any
// use, tree-summed (no serial acc chain). Expect VGPR ~72-88 and all 16 loads
// in flight; if time doesn't move, we're at a structural read-BW ceiling.

__device__ __forceinline__ float4 f4_add(float4 a, float4 b) {
    return make_float4(a.x + b.x, a.y + b.y, a.z + b.z, a.w + b.w);
}

__device__ __forceinline__ float4 f4_shfl_down(float4 v, int off) {
    return make_float4(__shfl_down(v.x, off, 64), __shfl_down(v.y, off, 64),
                       __shfl_down(v.z, off, 64), __shfl_down(v.w, off, 64));
}

__global__ __launch_bounds__(256) void coatt_colsum(const float* __restrict__ C,
                                                    const float* __restrict__ X1,
                                                    float* __restrict__ out) {
    const int lane = threadIdx.x & 63;
    const int wv   = (blockIdx.x << 2) + (threadIdx.x >> 6);  // global wave id
    const int b    = wv >> 1;          // batch element
    const int isC  = wv & 1;           // 0 -> X1 (out cols 0..31), 1 -> C (32..63)

    const float4* p = reinterpret_cast<const float4*>(
        isC ? (C + (size_t)b * NT * ND) : (X1 + (size_t)b * NS * ND));

    // 1024 float4s per slice; lane covers indices lane + 64k, k=0..15.
    // All 16 loads are independent and named -> compiler must issue them
    // back-to-back (16-deep MLP, ~64 VGPRs of destinations).
    float4 v0  = p[lane +   0];
    float4 v1  = p[lane +  64];
    float4 v2  = p[lane + 128];
    float4 v3  = p[lane + 192];
    float4 v4  = p[lane + 256];
    float4 v5  = p[lane + 320];
    float4 v6  = p[lane + 384];
    float4 v7  = p[lane + 448];
    float4 v8  = p[lane + 512];
    float4 v9  = p[lane + 576];
    float4 v10 = p[lane + 640];
    float4 v11 = p[lane + 704];
    float4 v12 = p[lane + 768];
    float4 v13 = p[lane + 832];
    float4 v14 = p[lane + 896];
    float4 v15 = p[lane + 960];

    // Balanced tree sum (4 levels, no serial chain).
    float4 a0 = f4_add(v0, v1),   a1 = f4_add(v2, v3);
    float4 a2 = f4_add(v4, v5),   a3 = f4_add(v6, v7);
    float4 a4 = f4_add(v8, v9),   a5 = f4_add(v10, v11);
    float4 a6 = f4_add(v12, v13), a7 = f4_add(v14, v15);
    float4 b0 = f4_add(a0, a1),   b1 = f4_add(a2, a3);
    float4 b2 = f4_add(a4, a5),   b3 = f4_add(a6, a7);
    float4 s  = f4_add(f4_add(b0, b1), f4_add(b2, b3));

    // Combine the 8 row-groups; stride-8 lanes share a column chunk
    // (64 % 8 == 0 keeps chunk = lane & 7 loop-invariant).
    #pragma unroll
    for (int off = 32; off >= 8; off >>= 1) {
        s = f4_add(s, f4_shfl_down(s, off));
    }

    if (lane < 8) {
        float4* o = reinterpret_cast<float4*>(out + (size_t)b * 64 + isC * 32);
        o[lane] = s;
    }
}

extern "C" void kernel_launch(void* const* d_in, const int* in_sizes, int n_in,
                              void* d_out, int out_size, void* d_ws, size_t ws_size,
                              hipStream_t stream) {
    // setup_inputs order: C, X1, W, Ws, Wc, was, wac
    const float* C  = (const float*)d_in[0];
    const float* X1 = (const float*)d_in[1];
    float* out = (float*)d_out;   // (B,1,64) fp32

    coatt_colsum<<<(NB * 2) / 4, 256, 0, stream>>>(C, X1, out);
}